// Round 1
// baseline (597.756 us; speedup 1.0000x reference)
//
#include <hip/hip_runtime.h>
#include <hip/hip_fp16.h>

#define NB 64
#define NS 512
#define NH 1024
#define NITERS 10

// -log(512)
#define LOG_INV_NS (-6.238324625039508f)

using half8 = _Float16 __attribute__((ext_vector_type(8)));
using f32x4 = float __attribute__((ext_vector_type(4)));

// ---------------------------------------------------------------------------
// Kernel 1: row L2 norms for x and y. One wave per row (1024 floats).
// rows [0, 32768) -> x, [32768, 65536) -> y
__global__ __launch_bounds__(256) void norms_kernel(
    const float* __restrict__ x, const float* __restrict__ y,
    float* __restrict__ inv_nx, float* __restrict__ inv_ny) {
  int wid = threadIdx.x >> 6, lane = threadIdx.x & 63;
  int row = blockIdx.x * 4 + wid;  // 0..65535
  const float* base = (row < NB * NS) ? (x + (size_t)row * NH)
                                      : (y + (size_t)(row - NB * NS) * NH);
  const float4* p = (const float4*)base;
  float s = 0.f;
#pragma unroll
  for (int j = 0; j < 4; ++j) {
    float4 v = p[j * 64 + lane];
    s += v.x * v.x + v.y * v.y + v.z * v.z + v.w * v.w;
  }
#pragma unroll
  for (int o = 32; o; o >>= 1) s += __shfl_xor(s, o, 64);
  if (lane == 0) {
    float inv = 1.0f / fmaxf(sqrtf(s), 1e-12f);
    if (row < NB * NS) inv_nx[row] = inv;
    else inv_ny[row - NB * NS] = inv;
  }
}

// ---------------------------------------------------------------------------
// Kernel 2: batched GEMM  S[b][m][n] = sum_k xn[b][m][k] * yn[b][n][k]
// f16 MFMA 16x16x32, 128x128 tile, 4 waves (each 64x64), BK=32.
// Normalization folded into LDS staging (fp32 load * inv_norm -> f16).
__global__ __launch_bounds__(256) void gemm_kernel(
    const float* __restrict__ x, const float* __restrict__ y,
    const float* __restrict__ inv_nx, const float* __restrict__ inv_ny,
    float* __restrict__ S) {
  __shared__ _Float16 As[128][40];  // row stride 80B: 16B-aligned, conflict at b128 floor
  __shared__ _Float16 Bs[128][40];

  int b = blockIdx.y;
  int tm = (blockIdx.x >> 2) * 128;
  int tn = (blockIdx.x & 3) * 128;
  int tid = threadIdx.x;
  int wid = tid >> 6, lane = tid & 63;
  int wr = (wid >> 1) * 64, wc = (wid & 1) * 64;
  int fr = lane & 15, fq = lane >> 4;

  // staging: thread -> row tid>>1 (0..127), k-half (tid&1)*16
  int srow = tid >> 1;
  int skh = (tid & 1) * 16;
  const float* xb = x + ((size_t)b * NS + tm + srow) * NH + skh;
  const float* yb = y + ((size_t)b * NS + tn + srow) * NH + skh;
  float ax = inv_nx[b * NS + tm + srow];
  float ay = inv_ny[b * NS + tn + srow];

  f32x4 acc[4][4] = {};

  for (int k0 = 0; k0 < NH; k0 += 32) {
    __syncthreads();
    {
      const float4* px = (const float4*)(xb + k0);
      const float4* py = (const float4*)(yb + k0);
      alignas(16) _Float16 ta[16];
      alignas(16) _Float16 tb[16];
#pragma unroll
      for (int j = 0; j < 4; ++j) {
        float4 v = px[j];
        ta[4 * j + 0] = (_Float16)(v.x * ax);
        ta[4 * j + 1] = (_Float16)(v.y * ax);
        ta[4 * j + 2] = (_Float16)(v.z * ax);
        ta[4 * j + 3] = (_Float16)(v.w * ax);
      }
#pragma unroll
      for (int j = 0; j < 4; ++j) {
        float4 v = py[j];
        tb[4 * j + 0] = (_Float16)(v.x * ay);
        tb[4 * j + 1] = (_Float16)(v.y * ay);
        tb[4 * j + 2] = (_Float16)(v.z * ay);
        tb[4 * j + 3] = (_Float16)(v.w * ay);
      }
      *(half8*)&As[srow][skh + 0] = *(half8*)&ta[0];
      *(half8*)&As[srow][skh + 8] = *(half8*)&ta[8];
      *(half8*)&Bs[srow][skh + 0] = *(half8*)&tb[0];
      *(half8*)&Bs[srow][skh + 8] = *(half8*)&tb[8];
    }
    __syncthreads();

    half8 af[4], bf[4];
#pragma unroll
    for (int i = 0; i < 4; ++i) {
      af[i] = *(const half8*)&As[wr + 16 * i + fr][8 * fq];
      bf[i] = *(const half8*)&Bs[wc + 16 * i + fr][8 * fq];
    }
#pragma unroll
    for (int i = 0; i < 4; ++i)
#pragma unroll
      for (int j = 0; j < 4; ++j)
        acc[i][j] = __builtin_amdgcn_mfma_f32_16x16x32_f16(af[i], bf[j], acc[i][j], 0, 0, 0);
  }

  // C/D layout (m89-verified): col = lane&15, row = (lane>>4)*4 + reg
#pragma unroll
  for (int i = 0; i < 4; ++i)
#pragma unroll
    for (int j = 0; j < 4; ++j) {
      size_t base = ((size_t)b * NS + tm + wr + 16 * i + 4 * fq) * NS + tn + wc + 16 * j + fr;
#pragma unroll
      for (int p = 0; p < 4; ++p) S[base + (size_t)p * NS] = acc[i][j][p];
    }
}

// ---------------------------------------------------------------------------
// Kernel 3: init V=0, W=log_nu
__global__ __launch_bounds__(256) void init_kernel(float* __restrict__ V, float* __restrict__ W) {
  int i = blockIdx.x * 256 + threadIdx.x;  // 32768
  V[i] = 0.f;
  W[i] = LOG_INV_NS;
}

// ---------------------------------------------------------------------------
// Kernel 4 (u/row step): U[b][m] = log_mu - log( sum_n exp(f*S[b][m][n] + W[b][n]) )
// one wave per row; W staged in LDS.
__global__ __launch_bounds__(256) void u_kernel(
    const float* __restrict__ S, const float* __restrict__ W,
    float* __restrict__ U, float f) {
  __shared__ float4 Wl4[128];
  float* Wl = (float*)Wl4;
  int b = blockIdx.y;
  int tid = threadIdx.x;
  Wl[tid] = W[b * NS + tid];
  Wl[tid + 256] = W[b * NS + tid + 256];
  __syncthreads();

  int wid = tid >> 6, lane = tid & 63;
  int m = blockIdx.x * 4 + wid;
  const float4* row = (const float4*)(S + ((size_t)b * NS + m) * NS);
  float sum = 0.f;
#pragma unroll
  for (int j = 0; j < 2; ++j) {
    int c = j * 64 + lane;  // float4 chunk, n = 4c..4c+3
    float4 v = row[c];
    float4 w = Wl4[c];
    sum += __expf(fmaf(f, v.x, w.x));
    sum += __expf(fmaf(f, v.y, w.y));
    sum += __expf(fmaf(f, v.z, w.z));
    sum += __expf(fmaf(f, v.w, w.w));
  }
#pragma unroll
  for (int o = 32; o; o >>= 1) sum += __shfl_xor(sum, o, 64);
  if (lane == 0) U[b * NS + m] = LOG_INV_NS - logf(sum);
}

// ---------------------------------------------------------------------------
// Kernel 5 (v/col step): C(n) = sum_m exp(f*S + U(m)); V_new = log_nu - log C;
// W = 2*V_new - V_old. If last iter, also D(n) = sum_m S*exp(...) and emit
// per-block partial of sum_n (1/512) * D/C.
__global__ __launch_bounds__(256) void v_kernel(
    const float* __restrict__ S, const float* __restrict__ U,
    float* __restrict__ V, float* __restrict__ W,
    float f, int last, float* __restrict__ colpart) {
  __shared__ float Ul[512];
  __shared__ float red[256];
  int b = blockIdx.y;
  int tid = threadIdx.x;
  Ul[tid] = U[b * NS + tid];
  Ul[tid + 256] = U[b * NS + tid + 256];
  __syncthreads();

  int n = blockIdx.x * 256 + tid;
  const float* col = S + (size_t)b * NS * NS + n;
  float c = 0.f, d = 0.f;
#pragma unroll 8
  for (int m = 0; m < NS; ++m) {
    float s = col[(size_t)m * NS];
    float e = __expf(fmaf(f, s, Ul[m]));
    c += e;
    d = fmaf(s, e, d);
  }
  float vnew = LOG_INV_NS - logf(c);
  float vold = V[b * NS + n];
  V[b * NS + n] = vnew;
  W[b * NS + n] = 2.f * vnew - vold;

  if (last) {
    red[tid] = d / c;
    __syncthreads();
#pragma unroll
    for (int s2 = 128; s2 > 0; s2 >>= 1) {
      if (tid < s2) red[tid] += red[tid + s2];
      __syncthreads();
    }
    if (tid == 0) colpart[b * 2 + blockIdx.x] = red[0] * (1.0f / (float)NS);
  }
}

// ---------------------------------------------------------------------------
// Kernel 6: combine 2 partials per batch (deterministic, no atomics)
__global__ void combine_kernel(const float* __restrict__ colpart, float* __restrict__ out) {
  int b = threadIdx.x;  // 64 threads
  out[b] = colpart[2 * b] + colpart[2 * b + 1];
}

// ---------------------------------------------------------------------------
extern "C" void kernel_launch(void* const* d_in, const int* in_sizes, int n_in,
                              void* d_out, int out_size, void* d_ws, size_t ws_size,
                              hipStream_t stream) {
  (void)in_sizes; (void)n_in; (void)out_size; (void)ws_size;
  const float* x = (const float*)d_in[0];
  const float* y = (const float*)d_in[1];
  float* out = (float*)d_out;

  float* S = (float*)d_ws;                       // 64*512*512
  float* inv_nx = S + (size_t)NB * NS * NS;      // 32768
  float* inv_ny = inv_nx + NB * NS;
  float* U = inv_ny + NB * NS;
  float* V = U + NB * NS;
  float* W = V + NB * NS;
  float* colpart = W + NB * NS;                  // 128

  norms_kernel<<<(NB * NS * 2) / 4, 256, 0, stream>>>(x, y, inv_nx, inv_ny);
  gemm_kernel<<<dim3(16, NB), 256, 0, stream>>>(x, y, inv_nx, inv_ny, S);
  init_kernel<<<(NB * NS) / 256, 256, 0, stream>>>(V, W);

  for (int t = 1; t <= NITERS; ++t) {
    float f = 10.0f * (float)t;  // t * A = t * S / reg = 10 t S
    u_kernel<<<dim3(NS / 4, NB), 256, 0, stream>>>(S, W, U, f);
    v_kernel<<<dim3(2, NB), 256, 0, stream>>>(S, U, V, W, f, t == NITERS ? 1 : 0, colpart);
  }
  combine_kernel<<<1, 64, 0, stream>>>(colpart, out);
}